// Round 3
// baseline (578.039 us; speedup 1.0000x reference)
//
#include <hip/hip_runtime.h>
#include <hip/hip_bf16.h>
#include <stdint.h>

// Problem constants (Gemma3n attention block)
#define S_LEN 2048
#define HIDN  2048
#define NH    8
#define NKV   2
#define HD    256

typedef __bf16 v8bf __attribute__((ext_vector_type(8)));
typedef float  v4f  __attribute__((ext_vector_type(4)));
typedef unsigned short u16;

struct alignas(8) US4 { u16 x, y, z, w; };

__device__ __forceinline__ float b2f(u16 u) {
  union { unsigned int i; float f; } t; t.i = ((unsigned)u) << 16; return t.f;
}
__device__ __forceinline__ u16 f2b(float f) {
  __hip_bfloat16 h = __float2bfloat16(f);
  return *reinterpret_cast<u16*>(&h);
}

template <typename T>
__device__ __forceinline__ void gload16(const T* g, void* l) {
  __builtin_amdgcn_global_load_lds(
      (const __attribute__((address_space(1))) void*)g,
      (__attribute__((address_space(3))) void*)l, 16, 0, 0);
}

// ---------------- f32 -> bf16 cast, 4 elems/thread ----------------
__global__ void cvt_kernel(const float* __restrict__ in, u16* __restrict__ out, int n4) {
  int i = blockIdx.x * blockDim.x + threadIdx.x;
  if (i >= n4) return;
  float4 v = reinterpret_cast<const float4*>(in)[i];
  US4 o; o.x = f2b(v.x); o.y = f2b(v.y); o.z = f2b(v.z); o.w = f2b(v.w);
  reinterpret_cast<US4*>(out)[i] = o;
}

// ---------------- f32 -> (hi,lo) bf16 split, 4 elems/thread ----------------
__global__ void cvt_split_kernel(const float* __restrict__ in,
                                 u16* __restrict__ hi, u16* __restrict__ lo, int n4) {
  int i = blockIdx.x * blockDim.x + threadIdx.x;
  if (i >= n4) return;
  float4 v = reinterpret_cast<const float4*>(in)[i];
  US4 h, l;
  float x;
  x = v.x; h.x = f2b(x); l.x = f2b(x - b2f(h.x));
  x = v.y; h.y = f2b(x); l.y = f2b(x - b2f(h.y));
  x = v.z; h.z = f2b(x); l.z = f2b(x - b2f(h.z));
  x = v.w; h.w = f2b(x); l.w = f2b(x - b2f(h.w));
  reinterpret_cast<US4*>(hi)[i] = h;
  reinterpret_cast<US4*>(lo)[i] = l;
}

// ---------------- split-precision NT GEMM: C = (Ah+Al)(Bh+Bl)^T, f32 out ----
__global__ __launch_bounds__(256, 2) void gemm3_nt(
    const u16* __restrict__ Ah, const u16* __restrict__ Al,
    const u16* __restrict__ Bh, const u16* __restrict__ Bl,
    float* __restrict__ C, int M, int N, int K) {
  __shared__ u16 Ash[128 * 32];
  __shared__ u16 Asl[128 * 32];
  __shared__ u16 Bsh[128 * 32];
  __shared__ u16 Bsl[128 * 32];
  const int tid = threadIdx.x;
  const int w = tid >> 6, lane = tid & 63;
  const int m0 = blockIdx.x * 128, n0 = blockIdx.y * 128;
  const int wr = (w >> 1) * 64, wc = (w & 1) * 64;
  const int lr = lane & 15, lk = (lane >> 4) << 3;
  v4f acc[4][4] = {};
  for (int kt = 0; kt < K; kt += 32) {
    __syncthreads();
#pragma unroll
    for (int it = 0; it < 2; it++) {
      const int t = tid + it * 256;
      const int row = t >> 2, col = (t & 3) << 3;
      gload16(Ah + (size_t)(m0 + row) * K + kt + col, (char*)Ash + t * 16);
      gload16(Al + (size_t)(m0 + row) * K + kt + col, (char*)Asl + t * 16);
      gload16(Bh + (size_t)(n0 + row) * K + kt + col, (char*)Bsh + t * 16);
      gload16(Bl + (size_t)(n0 + row) * K + kt + col, (char*)Bsl + t * 16);
    }
    __syncthreads();
    v8bf afh[4], afl[4], bfh[4], bfl[4];
#pragma unroll
    for (int i = 0; i < 4; i++) {
      afh[i] = *reinterpret_cast<const v8bf*>(&Ash[(wr + i * 16 + lr) * 32 + lk]);
      afl[i] = *reinterpret_cast<const v8bf*>(&Asl[(wr + i * 16 + lr) * 32 + lk]);
      bfh[i] = *reinterpret_cast<const v8bf*>(&Bsh[(wc + i * 16 + lr) * 32 + lk]);
      bfl[i] = *reinterpret_cast<const v8bf*>(&Bsl[(wc + i * 16 + lr) * 32 + lk]);
    }
#pragma unroll
    for (int i = 0; i < 4; i++)
#pragma unroll
      for (int jn = 0; jn < 4; jn++) {
        acc[i][jn] = __builtin_amdgcn_mfma_f32_16x16x32_bf16(afh[i], bfh[jn], acc[i][jn], 0, 0, 0);
        acc[i][jn] = __builtin_amdgcn_mfma_f32_16x16x32_bf16(afh[i], bfl[jn], acc[i][jn], 0, 0, 0);
        acc[i][jn] = __builtin_amdgcn_mfma_f32_16x16x32_bf16(afl[i], bfh[jn], acc[i][jn], 0, 0, 0);
      }
  }
  const int rbase = m0 + wr + ((lane >> 4) << 2);
  const int cbase = n0 + wc + lr;
#pragma unroll
  for (int i = 0; i < 4; i++)
#pragma unroll
    for (int jn = 0; jn < 4; jn++) {
      const int col = cbase + jn * 16;
#pragma unroll
      for (int j = 0; j < 4; j++)
        C[(size_t)(rbase + i * 16 + j) * N + col] = acc[i][jn][j];
    }
}

// ---------------- single-precision NT GEMM (bf16 in, f32 out) ----------------
__global__ __launch_bounds__(256, 2) void gemm_nt(
    const u16* __restrict__ A, const u16* __restrict__ Bm,
    float* __restrict__ C, int M, int N, int K) {
  __shared__ u16 As[128 * 32];
  __shared__ u16 Bs[128 * 32];
  const int tid = threadIdx.x;
  const int w = tid >> 6, lane = tid & 63;
  const int m0 = blockIdx.x * 128, n0 = blockIdx.y * 128;
  const int wr = (w >> 1) * 64, wc = (w & 1) * 64;
  const int lr = lane & 15, lk = (lane >> 4) << 3;
  v4f acc[4][4] = {};
  const int row1 = tid >> 2, col1 = (tid & 3) << 3;
  const int t2 = tid + 256;
  const int row2 = t2 >> 2, col2 = (t2 & 3) << 3;
  for (int kt = 0; kt < K; kt += 32) {
    __syncthreads();
    gload16(A  + (size_t)(m0 + row1) * K + kt + col1, (char*)As + tid * 16);
    gload16(Bm + (size_t)(n0 + row1) * K + kt + col1, (char*)Bs + tid * 16);
    gload16(A  + (size_t)(m0 + row2) * K + kt + col2, (char*)As + t2 * 16);
    gload16(Bm + (size_t)(n0 + row2) * K + kt + col2, (char*)Bs + t2 * 16);
    __syncthreads();
    v8bf af[4], bfr[4];
#pragma unroll
    for (int i = 0; i < 4; i++) af[i]  = *reinterpret_cast<const v8bf*>(&As[(wr + i * 16 + lr) * 32 + lk]);
#pragma unroll
    for (int i = 0; i < 4; i++) bfr[i] = *reinterpret_cast<const v8bf*>(&Bs[(wc + i * 16 + lr) * 32 + lk]);
#pragma unroll
    for (int i = 0; i < 4; i++)
#pragma unroll
      for (int jn = 0; jn < 4; jn++)
        acc[i][jn] = __builtin_amdgcn_mfma_f32_16x16x32_bf16(af[i], bfr[jn], acc[i][jn], 0, 0, 0);
  }
  const int rbase = m0 + wr + ((lane >> 4) << 2);
  const int cbase = n0 + wc + lr;
#pragma unroll
  for (int i = 0; i < 4; i++)
#pragma unroll
    for (int jn = 0; jn < 4; jn++) {
      const int col = cbase + jn * 16;
#pragma unroll
      for (int j = 0; j < 4; j++)
        C[(size_t)(rbase + i * 16 + j) * N + col] = acc[i][jn][j];
    }
}

// ---------------- RMSNorm (+RoPE for Q,K) + hi/lo split + transpose ----------
// one wave per (b,s,unit); unit 0..7 = Q heads, 8..9 = K heads, 10..11 = V heads
__global__ __launch_bounds__(256, 4) void norm_rope_kernel(
    const float* __restrict__ qkv, const float* __restrict__ cosb, const float* __restrict__ sinb,
    const float* __restrict__ qw, const float* __restrict__ kw,
    u16* __restrict__ q_th, u16* __restrict__ q_tl,
    u16* __restrict__ k_th, u16* __restrict__ v_t) {
  const int task = blockIdx.x * 4 + (threadIdx.x >> 6);
  const int lane = threadIdx.x & 63;
  const int unit = task % 12;
  const int ms = task / 12;           // b*S + s
  const int b = ms >> 11, s = ms & 2047;
  const int d0 = lane << 2;
  const int col0 = (unit < 8) ? unit * 256 : 2048 + (unit - 8) * 256;
  const float4 xv = *reinterpret_cast<const float4*>(qkv + (size_t)ms * 3072 + col0 + d0);
  float x[4] = { xv.x, xv.y, xv.z, xv.w };
  float ss = x[0]*x[0] + x[1]*x[1] + x[2]*x[2] + x[3]*x[3];
#pragma unroll
  for (int m = 1; m < 64; m <<= 1) ss += __shfl_xor(ss, m, 64);
  const float r = rsqrtf(ss * (1.0f / 256.0f) + 1e-6f);
  if (unit < 10) {
    const float4 wv = *reinterpret_cast<const float4*>(((unit < 8) ? qw : kw) + d0);
    float xn[4];
    xn[0] = x[0] * r * wv.x; xn[1] = x[1] * r * wv.y;
    xn[2] = x[2] * r * wv.z; xn[3] = x[3] * r * wv.w;
    float rot[4];
#pragma unroll
    for (int j = 0; j < 4; j++) {
      const float p = __shfl(xn[j], lane ^ 32, 64);
      rot[j] = (lane < 32) ? -p : p;   // rotate_half: (-x2, x1)
    }
    const float4 c  = *reinterpret_cast<const float4*>(cosb + (size_t)ms * 256 + d0);
    const float4 sn = *reinterpret_cast<const float4*>(sinb + (size_t)ms * 256 + d0);
    float y[4];
    y[0] = xn[0] * c.x + rot[0] * sn.x;
    y[1] = xn[1] * c.y + rot[1] * sn.y;
    y[2] = xn[2] * c.z + rot[2] * sn.z;
    y[3] = xn[3] * c.w + rot[3] * sn.w;
    if (unit < 8) {
      const size_t dst = ((size_t)(b * NH + unit) * S_LEN + s) * 256 + d0;
      US4 oh, ol;
      oh.x = f2b(y[0]); ol.x = f2b(y[0] - b2f(oh.x));
      oh.y = f2b(y[1]); ol.y = f2b(y[1] - b2f(oh.y));
      oh.z = f2b(y[2]); ol.z = f2b(y[2] - b2f(oh.z));
      oh.w = f2b(y[3]); ol.w = f2b(y[3] - b2f(oh.w));
      *reinterpret_cast<US4*>(q_th + dst) = oh;
      *reinterpret_cast<US4*>(q_tl + dst) = ol;
    } else {
      const size_t dst = ((size_t)(b * NKV + (unit - 8)) * S_LEN + s) * 256 + d0;
      US4 oh;
      oh.x = f2b(y[0]); oh.y = f2b(y[1]); oh.z = f2b(y[2]); oh.w = f2b(y[3]);
      *reinterpret_cast<US4*>(k_th + dst) = oh;
    }
  } else {
    const int kvh = unit - 10;
    u16* vt = v_t + (size_t)(b * NKV + kvh) * 256 * 2048;   // [d][s] transposed
#pragma unroll
    for (int j = 0; j < 4; j++)
      vt[(size_t)(d0 + j) * 2048 + s] = f2b(x[j] * r);
  }
}

// ---------------- causal flash attention, split-K=2, 2-term QK^T -------------
// grid (16 qtiles, 16 bh, 2 halves); 8 waves x 16 q-rows (QB=128); KB=64
// LDS 80KB -> 2 blocks/CU, all 512 blocks co-resident. XOR slot-swizzle on
// K/V/P (slot ^= row&3); global_load_lds source pre-permuted (rule #21).
__global__ __launch_bounds__(512, 4) void attn_kernel(
    const u16* __restrict__ q_th, const u16* __restrict__ q_tl,
    const u16* __restrict__ k_th, const u16* __restrict__ v_t,
    u16* __restrict__ oP, float2* __restrict__ ml) {
  const int qt = 15 - blockIdx.x;   // heavy-first
  const int bh = blockIdx.y;
  const int z  = blockIdx.z;
  const int b = bh >> 3, h = bh & 7, hk = h >> 2;
  const int w = threadIdx.x >> 6, lane = threadIdx.x & 63;
  const int lr = lane & 15, ls = lane >> 4, lj = ls << 2;

  __shared__ u16 Ksh[8][64][32];   // 32KB, slot-swizzled
  __shared__ u16 Vts[2][256][32];  // 32KB, slot-swizzled
  __shared__ u16 Ps[8][2][16][32]; // 16KB, slot-swizzled

  const u16* qbh = q_th + ((size_t)(b * NH + h) * S_LEN + qt * 128) * 256;
  const u16* qbl = q_tl + ((size_t)(b * NH + h) * S_LEN + qt * 128) * 256;
  v8bf qfh[8], qfl[8];
#pragma unroll
  for (int f = 0; f < 8; f++) {
    qfh[f] = *reinterpret_cast<const v8bf*>(qbh + (w * 16 + lr) * 256 + f * 32 + ls * 8);
    qfl[f] = *reinterpret_cast<const v8bf*>(qbl + (w * 16 + lr) * 256 + f * 32 + ls * 8);
  }

  v4f o[16] = {};
  float mr[4] = { -1e30f, -1e30f, -1e30f, -1e30f };
  float lsum[4] = {};

  const u16* kbh = k_th + (size_t)(b * NKV + hk) * S_LEN * 256;
  const u16* vb  = v_t  + (size_t)(b * NKV + hk) * 256 * S_LEN;

  const int kt0 = z * (qt + 1);
  const int kt1 = kt0 + (qt + 1);
  for (int kt = kt0; kt < kt1; kt++) {
    __syncthreads();
#pragma unroll
    for (int it = 0; it < 4; it++) {
      const int t = threadIdx.x + it * 512;
      {
        const int slot = t & 3, kv = (t >> 2) & 63, ks = t >> 8;
        const int c8 = slot ^ (kv & 3);
        gload16(kbh + (size_t)(kt * 64 + kv) * 256 + ks * 32 + c8 * 8, (char*)Ksh + t * 16);
      }
      {
        const int slot = t & 3, d = (t >> 2) & 255, kss = t >> 10;
        const int c8 = slot ^ (d & 3);
        gload16(vb + (size_t)d * 2048 + kt * 64 + kss * 32 + c8 * 8, (char*)Vts + t * 16);
      }
    }
    __syncthreads();
    // QK^T, 2-term split precision (q_hi + q_lo) x k_hi
    v4f sacc[4] = {};
#pragma unroll
    for (int ks = 0; ks < 8; ks++) {
#pragma unroll
      for (int n = 0; n < 4; n++) {
        const int row = n * 16 + lr;
        const v8bf kf = *reinterpret_cast<const v8bf*>(&Ksh[ks][row][(ls ^ (lr & 3)) << 3]);
        sacc[n] = __builtin_amdgcn_mfma_f32_16x16x32_bf16(qfh[ks], kf, sacc[n], 0, 0, 0);
        sacc[n] = __builtin_amdgcn_mfma_f32_16x16x32_bf16(qfl[ks], kf, sacc[n], 0, 0, 0);
      }
    }
    if (kt >= 2 * qt) {
      const int rowg = qt * 128 + w * 16 + lj;
#pragma unroll
      for (int n = 0; n < 4; n++) {
        const int colg = kt * 64 + n * 16 + lr;
#pragma unroll
        for (int j = 0; j < 4; j++)
          if (colg > rowg + j) sacc[n][j] = -1e30f;
      }
    }
    // online softmax (row r = w*16+lj+j lives in 16 lanes sharing lane>>4)
    float pm[4];
#pragma unroll
    for (int j = 0; j < 4; j++)
      pm[j] = fmaxf(fmaxf(sacc[0][j], sacc[1][j]), fmaxf(sacc[2][j], sacc[3][j]));
#pragma unroll
    for (int m = 1; m < 16; m <<= 1)
#pragma unroll
      for (int j = 0; j < 4; j++)
        pm[j] = fmaxf(pm[j], __shfl_xor(pm[j], m, 64));
    float sc[4], rs[4];
#pragma unroll
    for (int j = 0; j < 4; j++) {
      const float mn = fmaxf(mr[j], pm[j]);
      sc[j] = __expf(mr[j] - mn);
      mr[j] = mn;
      rs[j] = 0.f;
    }
    u16 pb[4][4];
#pragma unroll
    for (int n = 0; n < 4; n++)
#pragma unroll
      for (int j = 0; j < 4; j++) {
        const float p = __expf(sacc[n][j] - mr[j]);
        rs[j] += p;
        pb[n][j] = f2b(p);
      }
#pragma unroll
    for (int m = 1; m < 16; m <<= 1)
#pragma unroll
      for (int j = 0; j < 4; j++)
        rs[j] += __shfl_xor(rs[j], m, 64);
#pragma unroll
    for (int j = 0; j < 4; j++)
      lsum[j] = lsum[j] * sc[j] + rs[j];
#pragma unroll
    for (int df = 0; df < 16; df++)
#pragma unroll
      for (int j = 0; j < 4; j++)
        o[df][j] *= sc[j];
    // P (C-layout) -> LDS (A-layout), wave-private, swizzled
#pragma unroll
    for (int n = 0; n < 4; n++)
#pragma unroll
      for (int j = 0; j < 4; j++) {
        const int slot = ((n & 1) << 1) | (lr >> 3);
        Ps[w][n >> 1][lj + j][((slot ^ j) << 3) + (lr & 7)] = pb[n][j];
      }
    // PV
#pragma unroll
    for (int kss = 0; kss < 2; kss++) {
      const v8bf pa = *reinterpret_cast<const v8bf*>(&Ps[w][kss][lr][(ls ^ (lr & 3)) << 3]);
#pragma unroll
      for (int df = 0; df < 16; df++) {
        const int d = df * 16 + lr;
        const v8bf vf = *reinterpret_cast<const v8bf*>(&Vts[kss][d][(ls ^ (lr & 3)) << 3]);
        o[df] = __builtin_amdgcn_mfma_f32_16x16x32_bf16(pa, vf, o[df], 0, 0, 0);
      }
    }
  }
  // write unnormalized partial (bf16) + (m, l)
  u16* ob = oP + ((((size_t)(z * 16 + bh)) * 16 + qt) * 128 + w * 16 + lj) * 256 + lr;
#pragma unroll
  for (int df = 0; df < 16; df++)
#pragma unroll
    for (int j = 0; j < 4; j++)
      ob[(size_t)j * 256 + df * 16] = f2b(o[df][j]);
  if (lr == 0) {
#pragma unroll
    for (int j = 0; j < 4; j++)
      ml[(((size_t)(z * 16 + bh)) * 16 + qt) * 128 + w * 16 + lj + j] =
          make_float2(mr[j], lsum[j]);
  }
}

// ---------------- split-K combine: merge 2 partials -> aout bf16 -------------
__global__ __launch_bounds__(256, 8) void combine_kernel(
    const u16* __restrict__ oP, const float2* __restrict__ ml,
    u16* __restrict__ aout) {
  const int wid = threadIdx.x >> 6, lane = threadIdx.x & 63;
  const int R = blockIdx.x * 4 + wid;          // 0..32767
  const int bh = R >> 11, rem = R & 2047, qt = rem >> 7, row = rem & 127;
  const int b = bh >> 3, h = bh & 7;
  const size_t i0 = (((size_t)bh)        * 16 + qt) * 128 + row;
  const size_t i1 = (((size_t)(16 + bh)) * 16 + qt) * 128 + row;
  const float2 m0 = ml[i0], m1 = ml[i1];
  const float ms = fmaxf(m0.x, m1.x);
  const float f0 = __expf(m0.x - ms), f1 = __expf(m1.x - ms);
  const float inv = 1.0f / (m0.y * f0 + m1.y * f1);
  const US4 a = reinterpret_cast<const US4*>(oP + i0 * 256)[lane];
  const US4 c = reinterpret_cast<const US4*>(oP + i1 * 256)[lane];
  US4 o;
  o.x = f2b((b2f(a.x) * f0 + b2f(c.x) * f1) * inv);
  o.y = f2b((b2f(a.y) * f0 + b2f(c.y) * f1) * inv);
  o.z = f2b((b2f(a.z) * f0 + b2f(c.z) * f1) * inv);
  o.w = f2b((b2f(a.w) * f0 + b2f(c.w) * f1) * inv);
  u16* dst = aout + ((size_t)(b * 2048 + qt * 128 + row)) * 2048 + h * 256 + lane * 4;
  *reinterpret_cast<US4*>(dst) = o;
}

extern "C" void kernel_launch(void* const* d_in, const int* in_sizes, int n_in,
                              void* d_out, int out_size, void* d_ws, size_t ws_size,
                              hipStream_t stream) {
  const float* hs   = (const float*)d_in[0];
  const float* cosb = (const float*)d_in[1];
  const float* sinb = (const float*)d_in[2];
  // d_in[3] attention_mask: exactly causal -> applied analytically in attn_kernel
  const float* Wq = (const float*)d_in[4];
  const float* Wk = (const float*)d_in[5];
  const float* Wv = (const float*)d_in[6];
  const float* Wo = (const float*)d_in[7];
  const float* qw = (const float*)d_in[8];
  const float* kw = (const float*)d_in[9];
  float* out = (float*)d_out;

  char* ws = (char*)d_ws;
  // Phase A/B buffers
  u16* hs_h = (u16*)(ws + 0);           // 16.78MB
  u16* hs_l = (u16*)(ws + 16777216);    // 16.78MB
  u16* wq_h = (u16*)(ws + 33554432);    // 12.58MB (Wq|Wk|Wv rows)
  u16* wq_l = (u16*)(ws + 46137344);    // 12.58MB
  u16* wo_b = (u16*)(ws + 58720256);    //  8.39MB
  float* qkv = (float*)(ws + 67108864); // 50.33MB f32 (ends 117,440,512)
  // Phase C+ aliases (producers of the aliased regions complete first)
  u16* q_th  = (u16*)(ws + 0);          // aliases hs_h
  u16* q_tl  = (u16*)(ws + 16777216);   // aliases hs_l
  u16* k_th  = (u16*)(ws + 33554432);   // aliases wq_h[0:4.19MB]
  u16* v_t   = (u16*)(ws + 37748736);   // aliases wq_h[4.19:8.39MB]
  u16* aout  = (u16*)(ws + 41943040);   // aliases wq_h tail + wq_l (16.78MB)
  u16* oP    = (u16*)(ws + 67108864);   // aliases qkv (33.55MB, bf16 partials)
  float2* mlp = (float2*)(ws + 100663296); // 0.52MB (m,l) pairs

  cvt_split_kernel<<<8192, 256, 0, stream>>>(hs, hs_h, hs_l, 2097152);
  cvt_split_kernel<<<4096, 256, 0, stream>>>(Wq, wq_h,           wq_l,           1048576);
  cvt_split_kernel<<<1024, 256, 0, stream>>>(Wk, wq_h + 4194304, wq_l + 4194304, 262144);
  cvt_split_kernel<<<1024, 256, 0, stream>>>(Wv, wq_h + 5242880, wq_l + 5242880, 262144);
  cvt_kernel<<<4096, 256, 0, stream>>>(Wo, wo_b, 1048576);

  gemm3_nt<<<dim3(32, 24), 256, 0, stream>>>(hs_h, hs_l, wq_h, wq_l, qkv, 4096, 3072, 2048);
  norm_rope_kernel<<<12288, 256, 0, stream>>>(qkv, cosb, sinb, qw, kw,
                                              q_th, q_tl, k_th, v_t);
  attn_kernel<<<dim3(16, 16, 2), 512, 0, stream>>>(q_th, q_tl, k_th, v_t, oP, mlp);
  combine_kernel<<<8192, 256, 0, stream>>>(oP, mlp, aout);
  gemm_nt<<<dim3(32, 16), 256, 0, stream>>>(aout, wo_b, out, 4096, 2048, 2048);
}

// Round 4
// 340.687 us; speedup vs baseline: 1.6967x; 1.6967x over previous
//
#include <hip/hip_runtime.h>
#include <hip/hip_bf16.h>
#include <stdint.h>

// Problem constants (Gemma3n attention block)
#define S_LEN 2048
#define HIDN  2048
#define NH    8
#define NKV   2
#define HD    256

typedef _Float16 v8h __attribute__((ext_vector_type(8)));
typedef float    v4f __attribute__((ext_vector_type(4)));
typedef unsigned short u16;

struct alignas(8) US4 { u16 x, y, z, w; };

__device__ __forceinline__ u16 f2h(float f) {
  union { _Float16 h; u16 u; } t; t.h = (_Float16)f; return t.u;
}
__device__ __forceinline__ float h2f(u16 u) {
  union { _Float16 h; u16 u; } t; t.u = u; return (float)t.h;
}

template <typename T>
__device__ __forceinline__ void gload16(const T* g, void* l) {
  __builtin_amdgcn_global_load_lds(
      (const __attribute__((address_space(1))) void*)g,
      (__attribute__((address_space(3))) void*)l, 16, 0, 0);
}

// ---------------- f32 -> f16 cast, 4 elems/thread ----------------
__global__ void cvt_h_kernel(const float* __restrict__ in, u16* __restrict__ out, int n4) {
  int i = blockIdx.x * blockDim.x + threadIdx.x;
  if (i >= n4) return;
  float4 v = reinterpret_cast<const float4*>(in)[i];
  US4 o; o.x = f2h(v.x); o.y = f2h(v.y); o.z = f2h(v.z); o.w = f2h(v.w);
  reinterpret_cast<US4*>(out)[i] = o;
}

// ---------------- f16 NT GEMM: C[m][n] = sum_k A[m][k]*B[n][k], f32 out ------
// 128x128 tile, BK=32, 4 waves (2x2 of 64x64), m97 structure.
__global__ __launch_bounds__(256, 2) void gemm_h_nt(
    const u16* __restrict__ A, const u16* __restrict__ Bm,
    float* __restrict__ C, int M, int N, int K) {
  __shared__ u16 As[128 * 32];
  __shared__ u16 Bs[128 * 32];
  const int tid = threadIdx.x;
  const int w = tid >> 6, lane = tid & 63;
  const int m0 = blockIdx.x * 128, n0 = blockIdx.y * 128;
  const int wr = (w >> 1) * 64, wc = (w & 1) * 64;
  const int lr = lane & 15, lk = (lane >> 4) << 3;
  v4f acc[4][4] = {};
  const int row1 = tid >> 2, col1 = (tid & 3) << 3;
  const int t2 = tid + 256;
  const int row2 = t2 >> 2, col2 = (t2 & 3) << 3;
  for (int kt = 0; kt < K; kt += 32) {
    __syncthreads();
    gload16(A  + (size_t)(m0 + row1) * K + kt + col1, (char*)As + tid * 16);
    gload16(Bm + (size_t)(n0 + row1) * K + kt + col1, (char*)Bs + tid * 16);
    gload16(A  + (size_t)(m0 + row2) * K + kt + col2, (char*)As + t2 * 16);
    gload16(Bm + (size_t)(n0 + row2) * K + kt + col2, (char*)Bs + t2 * 16);
    __syncthreads();
    v8h af[4], bfr[4];
#pragma unroll
    for (int i = 0; i < 4; i++) af[i]  = *reinterpret_cast<const v8h*>(&As[(wr + i * 16 + lr) * 32 + lk]);
#pragma unroll
    for (int i = 0; i < 4; i++) bfr[i] = *reinterpret_cast<const v8h*>(&Bs[(wc + i * 16 + lr) * 32 + lk]);
#pragma unroll
    for (int i = 0; i < 4; i++)
#pragma unroll
      for (int jn = 0; jn < 4; jn++)
        acc[i][jn] = __builtin_amdgcn_mfma_f32_16x16x32_f16(af[i], bfr[jn], acc[i][jn], 0, 0, 0);
  }
  const int rbase = m0 + wr + ((lane >> 4) << 2);
  const int cbase = n0 + wc + lr;
#pragma unroll
  for (int i = 0; i < 4; i++)
#pragma unroll
    for (int jn = 0; jn < 4; jn++) {
      const int col = cbase + jn * 16;
#pragma unroll
      for (int j = 0; j < 4; j++)
        C[(size_t)(rbase + i * 16 + j) * N + col] = acc[i][jn][j];
    }
}

// ---------------- RMSNorm (+RoPE for Q,K) + f16 store + V transpose ----------
// one wave per (b,s,unit); unit 0..7 = Q heads, 8..9 = K heads, 10..11 = V heads
__global__ __launch_bounds__(256, 4) void norm_rope_kernel(
    const float* __restrict__ qkv, const float* __restrict__ cosb, const float* __restrict__ sinb,
    const float* __restrict__ qw, const float* __restrict__ kw,
    u16* __restrict__ q_t, u16* __restrict__ k_t, u16* __restrict__ v_t) {
  const int task = blockIdx.x * 4 + (threadIdx.x >> 6);
  const int lane = threadIdx.x & 63;
  const int unit = task % 12;
  const int ms = task / 12;           // b*S + s
  const int b = ms >> 11, s = ms & 2047;
  const int d0 = lane << 2;
  const int col0 = (unit < 8) ? unit * 256 : 2048 + (unit - 8) * 256;
  const float4 xv = *reinterpret_cast<const float4*>(qkv + (size_t)ms * 3072 + col0 + d0);
  float x[4] = { xv.x, xv.y, xv.z, xv.w };
  float ss = x[0]*x[0] + x[1]*x[1] + x[2]*x[2] + x[3]*x[3];
#pragma unroll
  for (int m = 1; m < 64; m <<= 1) ss += __shfl_xor(ss, m, 64);
  const float r = rsqrtf(ss * (1.0f / 256.0f) + 1e-6f);
  if (unit < 10) {
    const float4 wv = *reinterpret_cast<const float4*>(((unit < 8) ? qw : kw) + d0);
    float xn[4];
    xn[0] = x[0] * r * wv.x; xn[1] = x[1] * r * wv.y;
    xn[2] = x[2] * r * wv.z; xn[3] = x[3] * r * wv.w;
    float rot[4];
#pragma unroll
    for (int j = 0; j < 4; j++) {
      const float p = __shfl(xn[j], lane ^ 32, 64);
      rot[j] = (lane < 32) ? -p : p;   // rotate_half: (-x2, x1)
    }
    const float4 c  = *reinterpret_cast<const float4*>(cosb + (size_t)ms * 256 + d0);
    const float4 sn = *reinterpret_cast<const float4*>(sinb + (size_t)ms * 256 + d0);
    US4 o;
    o.x = f2h(xn[0] * c.x + rot[0] * sn.x);
    o.y = f2h(xn[1] * c.y + rot[1] * sn.y);
    o.z = f2h(xn[2] * c.z + rot[2] * sn.z);
    o.w = f2h(xn[3] * c.w + rot[3] * sn.w);
    if (unit < 8) {
      const size_t dst = ((size_t)(b * NH + unit) * S_LEN + s) * 256 + d0;
      *reinterpret_cast<US4*>(q_t + dst) = o;
    } else {
      const size_t dst = ((size_t)(b * NKV + (unit - 8)) * S_LEN + s) * 256 + d0;
      *reinterpret_cast<US4*>(k_t + dst) = o;
    }
  } else {
    const int kvh = unit - 10;
    u16* vt = v_t + (size_t)(b * NKV + kvh) * 256 * 2048;   // [d][s] transposed
#pragma unroll
    for (int j = 0; j < 4; j++)
      vt[(size_t)(d0 + j) * 2048 + s] = f2h(x[j] * r);
  }
}

// ---------------- causal flash attention, fp16, split-K=2 --------------------
// grid (64 = 32 qtiles x 2 z heavy-first, 16 bh); 512 thr = 8 waves =
// 4 row-groups x 2 halves. QB=64, KB=64. Wave (g,hf): QK^T cols [32hf,32hf+32),
// PV d [128hf,128hf+128). LDS 73KB -> 2 blocks/CU. Swizzle slot^=(row>>1)&3
// (global_load_lds dest linear, source pre-permuted; read same involution).
__global__ __launch_bounds__(512, 2) void attn_kernel(
    const u16* __restrict__ q_t, const u16* __restrict__ k_t,
    const u16* __restrict__ v_t, u16* __restrict__ oP, float2* __restrict__ ml) {
  const int qt = 31 - (blockIdx.x >> 1);
  const int z  = blockIdx.x & 1;
  const int bh = blockIdx.y;
  const int b = bh >> 3, h = bh & 7, hk = h >> 2;
  const int wv = threadIdx.x >> 6, lane = threadIdx.x & 63;
  const int g = wv >> 1, hf = wv & 1;
  const int lr = lane & 15, ls = lane >> 4;

  __shared__ u16 Ksh[8][64][32];    // 32KB [d-chunk][kv][d%32] swizzled
  __shared__ u16 Vts[2][256][32];   // 32KB [kv-chunk][d][kv%32] swizzled
  __shared__ u16 Pp[4][2][16][32];  //  8KB [group][kv-chunk][qrow][kv%32] swz
  __shared__ float Mex[4][2][16];
  __shared__ float Lex[4][2][16];

  // Q fragments: 16 rows (qt*64 + g*16 + lr), full d=256 (persistent, 32 VGPR)
  const u16* qb = q_t + ((size_t)(b * NH + h) * S_LEN + qt * 64 + g * 16) * 256;
  v8h qf[8];
#pragma unroll
  for (int f = 0; f < 8; f++)
    qf[f] = *reinterpret_cast<const v8h*>(qb + lr * 256 + f * 32 + ls * 8);

  v4f o[8] = {};
  float mr[4] = { -1e30f, -1e30f, -1e30f, -1e30f };
  float lsum[4] = {};

  const u16* kb = k_t + (size_t)(b * NKV + hk) * S_LEN * 256;
  const u16* vb = v_t + (size_t)(b * NKV + hk) * 256 * S_LEN;

  const int ntile = qt + 1;
  const int c0 = (ntile + 1) >> 1;
  const int kt0 = z ? c0 : 0;
  const int kt1 = z ? ntile : c0;

  for (int kt = kt0; kt < kt1; kt++) {
    __syncthreads();
#pragma unroll
    for (int it = 0; it < 4; it++) {
      const int t = threadIdx.x + it * 512;
      {
        const int slot = t & 3, kv = (t >> 2) & 63, ks = t >> 8;
        const int c8 = slot ^ ((kv >> 1) & 3);
        gload16(kb + (size_t)(kt * 64 + kv) * 256 + ks * 32 + c8 * 8, (char*)Ksh + t * 16);
      }
      {
        const int slot = t & 3, d = (t >> 2) & 255, kss = t >> 10;
        const int c8 = slot ^ ((d >> 1) & 3);
        gload16(vb + (size_t)d * 2048 + kt * 64 + kss * 32 + c8 * 8, (char*)Vts + t * 16);
      }
    }
    __syncthreads();
    // QK^T: this wave's 32 columns
    v4f sacc[2] = {};
#pragma unroll
    for (int ks = 0; ks < 8; ks++) {
#pragma unroll
      for (int n = 0; n < 2; n++) {
        const int row = hf * 32 + n * 16 + lr;
        const v8h kf = *reinterpret_cast<const v8h*>(
            &Ksh[ks][row][(ls ^ ((row >> 1) & 3)) << 3]);
        sacc[n] = __builtin_amdgcn_mfma_f32_16x16x32_f16(qf[ks], kf, sacc[n], 0, 0, 0);
      }
    }
    if (kt == qt) {
#pragma unroll
      for (int n = 0; n < 2; n++)
#pragma unroll
        for (int j = 0; j < 4; j++) {
          const int rl = g * 16 + ls * 4 + j;
          const int cl = hf * 32 + n * 16 + lr;
          if (cl > rl) sacc[n][j] = -1e30f;
        }
    }
    // partial row-max over this wave's 32 cols (rows indexed by (ls, j))
    float pm[4];
#pragma unroll
    for (int j = 0; j < 4; j++) pm[j] = fmaxf(sacc[0][j], sacc[1][j]);
#pragma unroll
    for (int m = 1; m < 16; m <<= 1)
#pragma unroll
      for (int j = 0; j < 4; j++) pm[j] = fmaxf(pm[j], __shfl_xor(pm[j], m, 64));
    if (lr == 0)
#pragma unroll
      for (int j = 0; j < 4; j++) Mex[g][hf][ls * 4 + j] = pm[j];
    __syncthreads();
    float sc[4];
#pragma unroll
    for (int j = 0; j < 4; j++) {
      const float mo = Mex[g][hf ^ 1][ls * 4 + j];
      const float mn = fmaxf(mr[j], fmaxf(pm[j], mo));
      sc[j] = __expf(mr[j] - mn);
      mr[j] = mn;
    }
    // exp + partial row-sum + P -> LDS (kss plane = hf), swizzled
    float rs[4] = {};
#pragma unroll
    for (int n = 0; n < 2; n++)
#pragma unroll
      for (int j = 0; j < 4; j++) {
        const float p = __expf(sacc[n][j] - mr[j]);
        rs[j] += p;
        const int row = ls * 4 + j;
        const int chi = (n * 2 + (lr >> 3)) ^ ((row >> 1) & 3);
        Pp[g][hf][row][chi * 8 + (lr & 7)] = f2h(p);
      }
#pragma unroll
    for (int m = 1; m < 16; m <<= 1)
#pragma unroll
      for (int j = 0; j < 4; j++) rs[j] += __shfl_xor(rs[j], m, 64);
    if (lr == 0)
#pragma unroll
      for (int j = 0; j < 4; j++) Lex[g][hf][ls * 4 + j] = rs[j];
    __syncthreads();
#pragma unroll
    for (int j = 0; j < 4; j++)
      lsum[j] = lsum[j] * sc[j] + rs[j] + Lex[g][hf ^ 1][ls * 4 + j];
#pragma unroll
    for (int df = 0; df < 8; df++)
#pragma unroll
      for (int j = 0; j < 4; j++) o[df][j] *= sc[j];
    // PV: this wave's d-half over full 64 kv
#pragma unroll
    for (int kss = 0; kss < 2; kss++) {
      const v8h pa = *reinterpret_cast<const v8h*>(
          &Pp[g][kss][lr][(ls ^ ((lr >> 1) & 3)) << 3]);
#pragma unroll
      for (int df = 0; df < 8; df++) {
        const int d = hf * 128 + df * 16 + lr;
        const v8h vf = *reinterpret_cast<const v8h*>(
            &Vts[kss][d][(ls ^ ((d >> 1) & 3)) << 3]);
        o[df] = __builtin_amdgcn_mfma_f32_16x16x32_f16(pa, vf, o[df], 0, 0, 0);
      }
    }
  }
  // unnormalized partial (f16) + (m, l)
  u16* ob = oP + ((((size_t)(z * 16 + bh)) * 32 + qt) * 64 + g * 16 + ls * 4) * 256
               + hf * 128 + lr;
#pragma unroll
  for (int df = 0; df < 8; df++)
#pragma unroll
    for (int j = 0; j < 4; j++)
      ob[(size_t)j * 256 + df * 16] = f2h(o[df][j]);
  if (hf == 0 && lr == 0)
#pragma unroll
    for (int j = 0; j < 4; j++)
      ml[(((size_t)(z * 16 + bh)) * 32 + qt) * 64 + g * 16 + ls * 4 + j] =
          make_float2(mr[j], lsum[j]);
}

// ---------------- split-K combine: merge 2 partials -> aout f16 --------------
__global__ __launch_bounds__(256, 8) void combine_kernel(
    const u16* __restrict__ oP, const float2* __restrict__ ml,
    u16* __restrict__ aout) {
  const int wid = threadIdx.x >> 6, lane = threadIdx.x & 63;
  const int R = blockIdx.x * 4 + wid;          // 0..32767 = (bh, qt, row)
  const int bh = R >> 11, rem = R & 2047, qt = rem >> 6, row = rem & 63;
  const int b = bh >> 3, h = bh & 7;
  const size_t i0 = (((size_t)bh)      * 32 + qt) * 64 + row;
  const size_t i1 = (((size_t)(16+bh)) * 32 + qt) * 64 + row;
  const float2 m0 = ml[i0], m1 = ml[i1];
  const float ms = fmaxf(m0.x, m1.x);
  const float f0 = __expf(m0.x - ms), f1 = __expf(m1.x - ms);
  const float inv = 1.0f / (m0.y * f0 + m1.y * f1);
  const US4 a = reinterpret_cast<const US4*>(oP + i0 * 256)[lane];
  const US4 c = reinterpret_cast<const US4*>(oP + i1 * 256)[lane];
  US4 o;
  o.x = f2h((h2f(a.x) * f0 + h2f(c.x) * f1) * inv);
  o.y = f2h((h2f(a.y) * f0 + h2f(c.y) * f1) * inv);
  o.z = f2h((h2f(a.z) * f0 + h2f(c.z) * f1) * inv);
  o.w = f2h((h2f(a.w) * f0 + h2f(c.w) * f1) * inv);
  u16* dst = aout + ((size_t)(b * 2048 + qt * 64 + row)) * 2048 + h * 256 + lane * 4;
  *reinterpret_cast<US4*>(dst) = o;
}

extern "C" void kernel_launch(void* const* d_in, const int* in_sizes, int n_in,
                              void* d_out, int out_size, void* d_ws, size_t ws_size,
                              hipStream_t stream) {
  const float* hs   = (const float*)d_in[0];
  const float* cosb = (const float*)d_in[1];
  const float* sinb = (const float*)d_in[2];
  // d_in[3] attention_mask: exactly causal -> applied analytically in attn_kernel
  const float* Wq = (const float*)d_in[4];
  const float* Wk = (const float*)d_in[5];
  const float* Wv = (const float*)d_in[6];
  const float* Wo = (const float*)d_in[7];
  const float* qw = (const float*)d_in[8];
  const float* kw = (const float*)d_in[9];
  float* out = (float*)d_out;

  char* ws = (char*)d_ws;
  u16* hs_f = (u16*)(ws + 0);            // 16.78MB f16 (4096x2048)
  u16* w_f  = (u16*)(ws + 16777216);     // 12.58MB f16 (Wq|Wk|Wv rows, 3072x2048)
  u16* wo_f = (u16*)(ws + 29360128);     //  8.39MB f16 (2048x2048)
  float* qkv = (float*)(ws + 37748736);  // 50.33MB f32 (ends 88,080,384)
  u16* q_t  = (u16*)(ws + 88080384);     // 16.78MB f16 (B,NH,S,HD)
  u16* k_t  = (u16*)(ws + 104857600);    //  4.19MB f16 (B,NKV,S,HD)
  u16* v_t  = (u16*)(ws + 109051904);    //  4.19MB f16 (B,NKV,HD,S)  ends 113.2MB
  // late-phase aliases (producers of aliased regions are complete first)
  u16* oP   = (u16*)(ws + 37748736);     // 33.55MB f16 partials (aliases qkv)
  float2* mlp = (float2*)(ws + 71303168);// 0.52MB (aliases qkv tail)
  u16* aout = (u16*)(ws + 0);            // 16.78MB f16 (aliases hs_f)

  cvt_h_kernel<<<8192, 256, 0, stream>>>(hs, hs_f, 2097152);
  cvt_h_kernel<<<4096, 256, 0, stream>>>(Wq, w_f,           1048576);
  cvt_h_kernel<<<1024, 256, 0, stream>>>(Wk, w_f + 4194304, 262144);
  cvt_h_kernel<<<1024, 256, 0, stream>>>(Wv, w_f + 5242880, 262144);
  cvt_h_kernel<<<4096, 256, 0, stream>>>(Wo, wo_f,          1048576);

  gemm_h_nt<<<dim3(32, 24), 256, 0, stream>>>(hs_f, w_f, qkv, 4096, 3072, 2048);
  norm_rope_kernel<<<12288, 256, 0, stream>>>(qkv, cosb, sinb, qw, kw, q_t, k_t, v_t);
  attn_kernel<<<dim3(64, 16), 512, 0, stream>>>(q_t, k_t, v_t, oP, mlp);
  combine_kernel<<<8192, 256, 0, stream>>>(oP, mlp, aout);
  gemm_h_nt<<<dim3(32, 16), 256, 0, stream>>>(aout, wo_f, out, 4096, 2048, 2048);
}

// Round 5
// 273.026 us; speedup vs baseline: 2.1172x; 1.2478x over previous
//
#include <hip/hip_runtime.h>
#include <hip/hip_bf16.h>
#include <stdint.h>

// Problem constants (Gemma3n attention block)
#define S_LEN 2048
#define HIDN  2048
#define NH    8
#define NKV   2
#define HD    256

typedef _Float16 v8h __attribute__((ext_vector_type(8)));
typedef float    v4f __attribute__((ext_vector_type(4)));
typedef unsigned short u16;

struct alignas(8) US4 { u16 x, y, z, w; };

__device__ __forceinline__ u16 f2h(float f) {
  union { _Float16 h; u16 u; } t; t.h = (_Float16)f; return t.u;
}
__device__ __forceinline__ float h2f(u16 u) {
  union { _Float16 h; u16 u; } t; t.u = u; return (float)t.h;
}

template <typename T>
__device__ __forceinline__ void gload16(const T* g, void* l) {
  __builtin_amdgcn_global_load_lds(
      (const __attribute__((address_space(1))) void*)g,
      (__attribute__((address_space(3))) void*)l, 16, 0, 0);
}

// ---------------- f32 -> f16 cast, 4 elems/thread ----------------
__global__ void cvt_h_kernel(const float* __restrict__ in, u16* __restrict__ out, int n4) {
  int i = blockIdx.x * blockDim.x + threadIdx.x;
  if (i >= n4) return;
  float4 v = reinterpret_cast<const float4*>(in)[i];
  US4 o; o.x = f2h(v.x); o.y = f2h(v.y); o.z = f2h(v.z); o.w = f2h(v.w);
  reinterpret_cast<US4*>(out)[i] = o;
}

// ---------------- f16 NT GEMM: C[m][n] = sum_k A[m][k]*B[n][k], f32 out ------
// 128x128 tile, BK=32, 4 waves (2x2 of 64x64), m97 structure.
__global__ __launch_bounds__(256, 2) void gemm_h_nt(
    const u16* __restrict__ A, const u16* __restrict__ Bm,
    float* __restrict__ C, int M, int N, int K) {
  __shared__ u16 As[128 * 32];
  __shared__ u16 Bs[128 * 32];
  const int tid = threadIdx.x;
  const int w = tid >> 6, lane = tid & 63;
  const int m0 = blockIdx.x * 128, n0 = blockIdx.y * 128;
  const int wr = (w >> 1) * 64, wc = (w & 1) * 64;
  const int lr = lane & 15, lk = (lane >> 4) << 3;
  v4f acc[4][4] = {};
  const int row1 = tid >> 2, col1 = (tid & 3) << 3;
  const int t2 = tid + 256;
  const int row2 = t2 >> 2, col2 = (t2 & 3) << 3;
  for (int kt = 0; kt < K; kt += 32) {
    __syncthreads();
    gload16(A  + (size_t)(m0 + row1) * K + kt + col1, (char*)As + tid * 16);
    gload16(Bm + (size_t)(n0 + row1) * K + kt + col1, (char*)Bs + tid * 16);
    gload16(A  + (size_t)(m0 + row2) * K + kt + col2, (char*)As + t2 * 16);
    gload16(Bm + (size_t)(n0 + row2) * K + kt + col2, (char*)Bs + t2 * 16);
    __syncthreads();
    v8h af[4], bfr[4];
#pragma unroll
    for (int i = 0; i < 4; i++) af[i]  = *reinterpret_cast<const v8h*>(&As[(wr + i * 16 + lr) * 32 + lk]);
#pragma unroll
    for (int i = 0; i < 4; i++) bfr[i] = *reinterpret_cast<const v8h*>(&Bs[(wc + i * 16 + lr) * 32 + lk]);
#pragma unroll
    for (int i = 0; i < 4; i++)
#pragma unroll
      for (int jn = 0; jn < 4; jn++)
        acc[i][jn] = __builtin_amdgcn_mfma_f32_16x16x32_f16(af[i], bfr[jn], acc[i][jn], 0, 0, 0);
  }
  const int rbase = m0 + wr + ((lane >> 4) << 2);
  const int cbase = n0 + wc + lr;
#pragma unroll
  for (int i = 0; i < 4; i++)
#pragma unroll
    for (int jn = 0; jn < 4; jn++) {
      const int col = cbase + jn * 16;
#pragma unroll
      for (int j = 0; j < 4; j++)
        C[(size_t)(rbase + i * 16 + j) * N + col] = acc[i][jn][j];
    }
}

// ---------------- RMSNorm (+RoPE for Q,K) + f16 store + V transpose ----------
__global__ __launch_bounds__(256, 4) void norm_rope_kernel(
    const float* __restrict__ qkv, const float* __restrict__ cosb, const float* __restrict__ sinb,
    const float* __restrict__ qw, const float* __restrict__ kw,
    u16* __restrict__ q_t, u16* __restrict__ k_t, u16* __restrict__ v_t) {
  const int task = blockIdx.x * 4 + (threadIdx.x >> 6);
  const int lane = threadIdx.x & 63;
  const int unit = task % 12;
  const int ms = task / 12;           // b*S + s
  const int b = ms >> 11, s = ms & 2047;
  const int d0 = lane << 2;
  const int col0 = (unit < 8) ? unit * 256 : 2048 + (unit - 8) * 256;
  const float4 xv = *reinterpret_cast<const float4*>(qkv + (size_t)ms * 3072 + col0 + d0);
  float x[4] = { xv.x, xv.y, xv.z, xv.w };
  float ss = x[0]*x[0] + x[1]*x[1] + x[2]*x[2] + x[3]*x[3];
#pragma unroll
  for (int m = 1; m < 64; m <<= 1) ss += __shfl_xor(ss, m, 64);
  const float r = rsqrtf(ss * (1.0f / 256.0f) + 1e-6f);
  if (unit < 10) {
    const float4 wv = *reinterpret_cast<const float4*>(((unit < 8) ? qw : kw) + d0);
    float xn[4];
    xn[0] = x[0] * r * wv.x; xn[1] = x[1] * r * wv.y;
    xn[2] = x[2] * r * wv.z; xn[3] = x[3] * r * wv.w;
    float rot[4];
#pragma unroll
    for (int j = 0; j < 4; j++) {
      const float p = __shfl(xn[j], lane ^ 32, 64);
      rot[j] = (lane < 32) ? -p : p;   // rotate_half: (-x2, x1)
    }
    const float4 c  = *reinterpret_cast<const float4*>(cosb + (size_t)ms * 256 + d0);
    const float4 sn = *reinterpret_cast<const float4*>(sinb + (size_t)ms * 256 + d0);
    US4 o;
    o.x = f2h(xn[0] * c.x + rot[0] * sn.x);
    o.y = f2h(xn[1] * c.y + rot[1] * sn.y);
    o.z = f2h(xn[2] * c.z + rot[2] * sn.z);
    o.w = f2h(xn[3] * c.w + rot[3] * sn.w);
    if (unit < 8) {
      const size_t dst = ((size_t)(b * NH + unit) * S_LEN + s) * 256 + d0;
      *reinterpret_cast<US4*>(q_t + dst) = o;
    } else {
      const size_t dst = ((size_t)(b * NKV + (unit - 8)) * S_LEN + s) * 256 + d0;
      *reinterpret_cast<US4*>(k_t + dst) = o;
    }
  } else {
    const int kvh = unit - 10;
    u16* vt = v_t + (size_t)(b * NKV + kvh) * 256 * 2048;   // [d][s] transposed
#pragma unroll
    for (int j = 0; j < 4; j++)
      vt[(size_t)(d0 + j) * 2048 + s] = f2h(x[j] * r);
  }
}

// stage one K/V kv-tile (64 kv x 256 d each) into linear LDS buffers,
// global source pre-permuted to realize slot^=(row>>1)&3 swizzle (rule #21)
__device__ __forceinline__ void stage_tile(
    const u16* __restrict__ kb, const u16* __restrict__ vb, int kt,
    char* Ks, char* Vs, int tid) {
#pragma unroll
  for (int it = 0; it < 4; it++) {
    const int t = tid + it * 512;
    {
      const int slot = t & 3, kv = (t >> 2) & 63, ks = t >> 8;
      const int c8 = slot ^ ((kv >> 1) & 3);
      gload16(kb + (size_t)(kt * 64 + kv) * 256 + ks * 32 + c8 * 8, Ks + t * 16);
    }
    {
      const int slot = t & 3, d = (t >> 2) & 255, kss = t >> 10;
      const int c8 = slot ^ ((d >> 1) & 3);
      gload16(vb + (size_t)d * 2048 + kt * 64 + kss * 32 + c8 * 8, Vs + t * 16);
    }
  }
}

// ---------------- causal flash attention, fp16, QB=128, 2-phase dbuf ---------
// grid (16 qt, 16 bh); 512 thr = 8 waves, each owns 16 q-rows, full width.
// KB=64; LDS 144KB (2x(K32+V32)+P16) -> 1 block/CU; launch_bounds(512,2)
// => VGPR cap 256 (no spill). Counted vmcnt(8) + raw barriers: staging of
// tile kt+1 overlaps compute of tile kt (T3/T4 minimum 2-phase).
__global__ __launch_bounds__(512, 2) void attn_kernel(
    const u16* __restrict__ q_t, const u16* __restrict__ k_t,
    const u16* __restrict__ v_t, u16* __restrict__ aout) {
  const int qt = blockIdx.x;
  const int bh = blockIdx.y;
  const int b = bh >> 3, h = bh & 7, hk = h >> 2;
  const int tid = threadIdx.x;
  const int w = tid >> 6, lane = tid & 63;
  const int lr = lane & 15, ls = lane >> 4;

  __shared__ u16 KshB[2][8][64][32];   // 64KB [buf][d-chunk][kv][d%32] swz
  __shared__ u16 VtsB[2][2][256][32];  // 64KB [buf][kv-chunk][d][kv%32] swz
  __shared__ u16 Ps[8][2][16][32];     // 16KB per-wave P transpose, swz

  // Q fragments: rows qt*128 + w*16 + lr, full d=256 (32 VGPR)
  const u16* qb = q_t + ((size_t)(b * NH + h) * S_LEN + qt * 128 + w * 16) * 256;
  v8h qf[8];
#pragma unroll
  for (int f = 0; f < 8; f++)
    qf[f] = *reinterpret_cast<const v8h*>(qb + lr * 256 + f * 32 + ls * 8);

  v4f o[16] = {};
  float mr[4] = { -1e30f, -1e30f, -1e30f, -1e30f };
  float lsum[4] = {};

  const u16* kb = k_t + (size_t)(b * NKV + hk) * S_LEN * 256;
  const u16* vb = v_t + (size_t)(b * NKV + hk) * 256 * S_LEN;

  const int ntile = 2 * qt + 2;
  stage_tile(kb, vb, 0, (char*)KshB[0], (char*)VtsB[0], tid);

  for (int kt = 0; kt < ntile; kt++) {
    const int cb = kt & 1;
    if (kt + 1 < ntile) {
      stage_tile(kb, vb, kt + 1, (char*)KshB[cb ^ 1], (char*)VtsB[cb ^ 1], tid);
      asm volatile("s_waitcnt vmcnt(8)" ::: "memory");   // prev tile's loads done
    } else {
      asm volatile("s_waitcnt vmcnt(0)" ::: "memory");
    }
    __builtin_amdgcn_s_barrier();                        // all waves' tile ready
    __builtin_amdgcn_sched_barrier(0);

    // QK^T: 16 rows x 64 cols per wave
    v4f sacc[4] = {};
#pragma unroll
    for (int ks = 0; ks < 8; ks++) {
#pragma unroll
      for (int n = 0; n < 4; n++) {
        const int row = n * 16 + lr;
        const v8h kf = *reinterpret_cast<const v8h*>(
            &KshB[cb][ks][row][(ls ^ ((row >> 1) & 3)) << 3]);
        sacc[n] = __builtin_amdgcn_mfma_f32_16x16x32_f16(qf[ks], kf, sacc[n], 0, 0, 0);
      }
    }
    if (kt >= 2 * qt) {
      const int rowg = qt * 128 + w * 16 + ls * 4;
#pragma unroll
      for (int n = 0; n < 4; n++) {
        const int colg = kt * 64 + n * 16 + lr;
#pragma unroll
        for (int j = 0; j < 4; j++)
          if (colg > rowg + j) sacc[n][j] = -1e30f;
      }
    }
    // wave-local online softmax (rows ls*4+j live in 16 lanes sharing ls)
    float pm[4];
#pragma unroll
    for (int j = 0; j < 4; j++)
      pm[j] = fmaxf(fmaxf(sacc[0][j], sacc[1][j]), fmaxf(sacc[2][j], sacc[3][j]));
#pragma unroll
    for (int m = 1; m < 16; m <<= 1)
#pragma unroll
      for (int j = 0; j < 4; j++) pm[j] = fmaxf(pm[j], __shfl_xor(pm[j], m, 64));
    float sc[4], rs[4];
#pragma unroll
    for (int j = 0; j < 4; j++) {
      const float mn = fmaxf(mr[j], pm[j]);
      sc[j] = __expf(mr[j] - mn);
      mr[j] = mn;
      rs[j] = 0.f;
    }
#pragma unroll
    for (int n = 0; n < 4; n++)
#pragma unroll
      for (int j = 0; j < 4; j++) {
        const float p = __expf(sacc[n][j] - mr[j]);
        rs[j] += p;
        const int row = ls * 4 + j;
        const int chi = (((n & 1) << 1) | (lr >> 3)) ^ ((row >> 1) & 3);
        Ps[w][n >> 1][row][chi * 8 + (lr & 7)] = f2h(p);
      }
#pragma unroll
    for (int m = 1; m < 16; m <<= 1)
#pragma unroll
      for (int j = 0; j < 4; j++) rs[j] += __shfl_xor(rs[j], m, 64);
#pragma unroll
    for (int j = 0; j < 4; j++) lsum[j] = lsum[j] * sc[j] + rs[j];
#pragma unroll
    for (int df = 0; df < 16; df++)
#pragma unroll
      for (int j = 0; j < 4; j++) o[df][j] *= sc[j];
    // PV: full d=256 per wave
#pragma unroll
    for (int kss = 0; kss < 2; kss++) {
      const v8h pa = *reinterpret_cast<const v8h*>(
          &Ps[w][kss][lr][(ls ^ ((lr >> 1) & 3)) << 3]);
#pragma unroll
      for (int df = 0; df < 16; df++) {
        const int d = df * 16 + lr;
        const v8h vf = *reinterpret_cast<const v8h*>(
            &VtsB[cb][kss][d][(ls ^ ((d >> 1) & 3)) << 3]);
        o[df] = __builtin_amdgcn_mfma_f32_16x16x32_f16(pa, vf, o[df], 0, 0, 0);
      }
    }
    __builtin_amdgcn_s_barrier();   // all reads of buf cb done before restage
  }

  float inv[4];
#pragma unroll
  for (int j = 0; j < 4; j++) inv[j] = 1.0f / lsum[j];
  u16* ob = aout + ((size_t)(b * 2048 + qt * 128 + w * 16 + ls * 4)) * 2048 + h * 256 + lr;
#pragma unroll
  for (int df = 0; df < 16; df++)
#pragma unroll
    for (int j = 0; j < 4; j++)
      ob[(size_t)j * 2048 + df * 16] = f2h(o[df][j] * inv[j]);
}

extern "C" void kernel_launch(void* const* d_in, const int* in_sizes, int n_in,
                              void* d_out, int out_size, void* d_ws, size_t ws_size,
                              hipStream_t stream) {
  const float* hs   = (const float*)d_in[0];
  const float* cosb = (const float*)d_in[1];
  const float* sinb = (const float*)d_in[2];
  // d_in[3] attention_mask: exactly causal -> applied analytically in attn_kernel
  const float* Wq = (const float*)d_in[4];
  const float* Wk = (const float*)d_in[5];
  const float* Wv = (const float*)d_in[6];
  const float* Wo = (const float*)d_in[7];
  const float* qw = (const float*)d_in[8];
  const float* kw = (const float*)d_in[9];
  float* out = (float*)d_out;

  char* ws = (char*)d_ws;
  u16* hs_f = (u16*)(ws + 0);            // 16.78MB f16 (4096x2048)
  u16* w_f  = (u16*)(ws + 16777216);     // 12.58MB f16 (Wq|Wk|Wv rows, 3072x2048)
  u16* wo_f = (u16*)(ws + 29360128);     //  8.39MB f16 (2048x2048)
  float* qkv = (float*)(ws + 37748736);  // 50.33MB f32 (ends 88,080,384)
  u16* q_t  = (u16*)(ws + 88080384);     // 16.78MB f16 (B,NH,S,HD)
  u16* k_t  = (u16*)(ws + 104857600);    //  4.19MB f16 (B,NKV,S,HD)
  u16* v_t  = (u16*)(ws + 109051904);    //  4.19MB f16 (B,NKV,HD,S)  ends 113.2MB
  u16* aout = (u16*)(ws + 0);            // 16.78MB f16 (aliases hs_f, gemm1 done)

  cvt_h_kernel<<<8192, 256, 0, stream>>>(hs, hs_f, 2097152);
  cvt_h_kernel<<<4096, 256, 0, stream>>>(Wq, w_f,           1048576);
  cvt_h_kernel<<<1024, 256, 0, stream>>>(Wk, w_f + 4194304, 262144);
  cvt_h_kernel<<<1024, 256, 0, stream>>>(Wv, w_f + 5242880, 262144);
  cvt_h_kernel<<<4096, 256, 0, stream>>>(Wo, wo_f,          1048576);

  gemm_h_nt<<<dim3(32, 24), 256, 0, stream>>>(hs_f, w_f, qkv, 4096, 3072, 2048);
  norm_rope_kernel<<<12288, 256, 0, stream>>>(qkv, cosb, sinb, qw, kw, q_t, k_t, v_t);
  attn_kernel<<<dim3(16, 16), 512, 0, stream>>>(q_t, k_t, v_t, aout);
  gemm_h_nt<<<dim3(32, 16), 256, 0, stream>>>(aout, wo_f, out, 4096, 2048, 2048);
}